// Round 12
// baseline (913.319 us; speedup 1.0000x reference)
//
#include <hip/hip_runtime.h>
#include <hip/hip_cooperative_groups.h>

namespace cg = cooperative_groups;

#define NEG_SLOPE 0.2f
#define EPSV 1e-16f

__device__ __forceinline__ float lrelu(float e){ return (e > 0.f) ? e : NEG_SLOPE*e; }
__device__ __forceinline__ float bf2f(unsigned short u){ return __uint_as_float((unsigned)u << 16); }
__device__ __forceinline__ unsigned short f2bf(float f){
  unsigned u = __float_as_uint(f);
  u += 0x7FFFu + ((u >> 16) & 1u);        // RTNE
  return (unsigned short)(u >> 16);
}

// ---------------- CSR build: zero + degree + scan + fill, one cooperative kernel ----------------
__global__ void k_csr(const int* __restrict__ ei, int E, int N,
                      int* __restrict__ deg, int* __restrict__ cnt,
                      int* __restrict__ rs, int* __restrict__ csr_s,
                      int* __restrict__ bsum){
  cg::grid_group grid = cg::this_grid();
  const int nb = gridDim.x;              // launched with 1024
  int tid = threadIdx.x, bid = blockIdx.x;
  int gt = bid*blockDim.x + tid, gs = nb*blockDim.x;
  int ET = E + N;
  __shared__ int red[256];
  __shared__ int sc[1024];
  __shared__ int ts[256];

  // phase 0: zero deg/cnt
  for (int i = gt; i < N; i += gs){ deg[i] = 0; cnt[i] = 0; }
  grid.sync();
  // phase 1: degree histogram
  for (int t = gt; t < ET; t += gs){
    int dst = (t < E) ? ei[E + t] : (t - E);
    atomicAdd(&deg[dst], 1);
  }
  grid.sync();
  // phase 2a: per-block chunk sums
  int chunk = (N + nb - 1) / nb;
  int s0 = bid*chunk, e0 = min(s0 + chunk, N);
  {
    int sum = 0;
    for (int i = s0 + tid; i < e0; i += 256) sum += deg[i];
    red[tid] = sum; __syncthreads();
    for (int o = 128; o; o >>= 1){ if (tid < o) red[tid] += red[tid+o]; __syncthreads(); }
    if (tid == 0) bsum[bid] = red[0];
  }
  grid.sync();
  // phase 2b: block 0 exclusive-scans the 1024 block sums
  if (bid == 0){
    for (int i = tid; i < 1024; i += 256) sc[i] = (i < nb) ? bsum[i] : 0;
    __syncthreads();
    int a0 = sc[4*tid], a1 = sc[4*tid+1], a2 = sc[4*tid+2], a3 = sc[4*tid+3];
    int l1 = a0+a1, l2 = l1+a2, l3 = l2+a3;
    ts[tid] = l3; __syncthreads();
    for (int o = 1; o < 256; o <<= 1){
      int v = (tid >= o) ? ts[tid-o] : 0; __syncthreads();
      ts[tid] += v; __syncthreads();
    }
    int excl = (tid == 0) ? 0 : ts[tid-1];
    sc[4*tid] = excl; sc[4*tid+1] = excl+a0; sc[4*tid+2] = excl+l1; sc[4*tid+3] = excl+l2;
    __syncthreads();
    for (int i = tid; i < nb; i += 256) bsum[i] = sc[i];   // exclusive prefix
  }
  grid.sync();
  // phase 2c: write row starts
  if (tid == 0){
    int r = bsum[bid];
    for (int i = s0; i < e0; ++i){ rs[i] = r; r += deg[i]; }
    if (e0 == N) rs[N] = r;   // blocks past the end write the same total; benign
  }
  grid.sync();
  // phase 3: fill
  for (int t = gt; t < ET; t += gs){
    int src, dst;
    if (t < E){ src = ei[t]; dst = ei[E + t]; } else { src = dst = t - E; }
    int pos = atomicAdd(&cnt[dst], 1);
    csr_s[rs[dst] + pos] = src;
  }
}

// ---------------- layer 1 GEMM: h1 (bf16) = x @ W1, plus per-node attention terms ----------------
__global__ __launch_bounds__(256) void k_gemm1(const float* __restrict__ x, const float* __restrict__ W1,
                                               const float* __restrict__ a1s, const float* __restrict__ a1d,
                                               int N, unsigned short* __restrict__ h1b,
                                               float* __restrict__ als, float* __restrict__ ald){
  __shared__ float xs[8][128];
  int bn = blockIdx.x * 8;
  int tid = threadIdx.x;
  {
    int m = tid >> 5, k4 = tid & 31;       // one float4 per thread
    int node = bn + m;
    float4 v = (node < N) ? ((const float4*)x)[(size_t)node*32 + k4]
                          : make_float4(0.f,0.f,0.f,0.f);
    ((float4*)xs[m])[k4] = v;
  }
  __syncthreads();
  float acc[8];
  #pragma unroll
  for (int m = 0; m < 8; ++m) acc[m] = 0.f;
  int j = tid;
  for (int k = 0; k < 128; ++k){
    float w = W1[k*256 + j];
    #pragma unroll
    for (int m = 0; m < 8; ++m) acc[m] = fmaf(xs[m][k], w, acc[m]);
  }
  int head = j >> 6;
  int lane = j & 63;
  float cas = a1s[head*64 + lane];
  float cad = a1d[head*64 + lane];
  #pragma unroll
  for (int m = 0; m < 8; ++m){
    int node = bn + m;
    if (node < N) h1b[(size_t)node*256 + j] = f2bf(acc[m]);
    float vs = acc[m]*cas, vd = acc[m]*cad;
    #pragma unroll
    for (int o = 32; o; o >>= 1){ vs += __shfl_xor(vs, o, 64); vd += __shfl_xor(vd, o, 64); }
    if (lane == 0 && node < N){ als[node*4+head] = vs; ald[node*4+head] = vd; }
  }
}

// ---------------- layer 2 GEMM ----------------
__global__ __launch_bounds__(256) void k_gemm2(const float* __restrict__ z1, const float* __restrict__ W2,
                                               const float* __restrict__ a2s, const float* __restrict__ a2d,
                                               int N, float* __restrict__ h2,
                                               float* __restrict__ als, float* __restrict__ ald){
  __shared__ float zs[8][256];
  int bn = blockIdx.x * 8;
  int tid = threadIdx.x;
  {
    int m = tid >> 6, k4 = tid & 63;       // two float4 per thread
    int node = bn + m;
    const float4 zero = make_float4(0.f,0.f,0.f,0.f);
    ((float4*)zs[m])[k4]      = (node < N)   ? ((const float4*)z1)[(size_t)node*64 + k4] : zero;
    int m2 = m + 4, node2 = bn + m2;
    ((float4*)zs[m2])[k4]     = (node2 < N)  ? ((const float4*)z1)[(size_t)node2*64 + k4] : zero;
  }
  __syncthreads();
  int j = tid & 31;   // out channel
  int m = tid >> 5;   // node in block
  float acc = 0.f;
  for (int k = 0; k < 256; ++k) acc = fmaf(zs[m][k], W2[k*32 + j], acc);
  int node = bn + m;
  int head = j >> 4, lane = j & 15;
  if (node < N) h2[(size_t)node*32 + j] = acc;
  float vs = acc * a2s[head*16 + lane];
  float vd = acc * a2d[head*16 + lane];
  #pragma unroll
  for (int o = 8; o; o >>= 1){ vs += __shfl_xor(vs, o, 64); vd += __shfl_xor(vd, o, 64); }
  if (lane == 0 && node < N){ als[node*2+head] = vs; ald[node*2+head] = vd; }
}

// ---------------- fused softmax + aggregation, layer 1 (bf16 h1 gather) ----------------
__global__ __launch_bounds__(256) void k_agg1(const int* __restrict__ rs, const int* __restrict__ csr_s,
                                              const float* __restrict__ als, const float* __restrict__ ald,
                                              const unsigned short* __restrict__ h1b, const float* __restrict__ b1,
                                              int N, float* __restrict__ z1){
  __shared__ int    sidx[256];
  __shared__ float  sexp[256*4];
  __shared__ float4 accl[4][64];
  __shared__ float  sl[4][64];
  int node = blockIdx.x;
  int tid = threadIdx.x;
  int w = tid >> 6, lane = tid & 63;
  int head = lane >> 4;
  int beg = rs[node], end = rs[node+1];
  const ushort4* h1v = (const ushort4*)h1b;      // 4 bf16 (8B) per lane; row = 64 ushort4
  float4 acc = make_float4(0.f,0.f,0.f,0.f);
  float s = 0.f;
  for (int base = beg; base < end; base += 256){
    int cnt = min(256, end - base);
    if (tid < cnt) sidx[tid] = csr_s[base + tid];
    __syncthreads();
    for (int t = tid; t < cnt*4; t += 256){
      int e = t >> 2, h = t & 3;
      int sv = sidx[e];
      sexp[t] = __expf(lrelu(als[sv*4 + h] + ald[node*4 + h]));
    }
    __syncthreads();
    int e = w;
    for (; e + 12 < cnt; e += 16){
      int s0 = sidx[e], s1 = sidx[e+4], s2 = sidx[e+8], s3 = sidx[e+12];
      float x0 = sexp[e*4+head], x1 = sexp[(e+4)*4+head];
      float x2 = sexp[(e+8)*4+head], x3 = sexp[(e+12)*4+head];
      ushort4 u0 = h1v[(size_t)s0*64 + lane];
      ushort4 u1 = h1v[(size_t)s1*64 + lane];
      ushort4 u2 = h1v[(size_t)s2*64 + lane];
      ushort4 u3 = h1v[(size_t)s3*64 + lane];
      acc.x = fmaf(bf2f(u0.x), x0, acc.x); acc.y = fmaf(bf2f(u0.y), x0, acc.y);
      acc.z = fmaf(bf2f(u0.z), x0, acc.z); acc.w = fmaf(bf2f(u0.w), x0, acc.w);
      acc.x = fmaf(bf2f(u1.x), x1, acc.x); acc.y = fmaf(bf2f(u1.y), x1, acc.y);
      acc.z = fmaf(bf2f(u1.z), x1, acc.z); acc.w = fmaf(bf2f(u1.w), x1, acc.w);
      acc.x = fmaf(bf2f(u2.x), x2, acc.x); acc.y = fmaf(bf2f(u2.y), x2, acc.y);
      acc.z = fmaf(bf2f(u2.z), x2, acc.z); acc.w = fmaf(bf2f(u2.w), x2, acc.w);
      acc.x = fmaf(bf2f(u3.x), x3, acc.x); acc.y = fmaf(bf2f(u3.y), x3, acc.y);
      acc.z = fmaf(bf2f(u3.z), x3, acc.z); acc.w = fmaf(bf2f(u3.w), x3, acc.w);
      s += (x0 + x1) + (x2 + x3);
    }
    for (; e < cnt; e += 4){
      int s0 = sidx[e];
      float x0 = sexp[e*4+head];
      ushort4 u0 = h1v[(size_t)s0*64 + lane];
      acc.x = fmaf(bf2f(u0.x), x0, acc.x); acc.y = fmaf(bf2f(u0.y), x0, acc.y);
      acc.z = fmaf(bf2f(u0.z), x0, acc.z); acc.w = fmaf(bf2f(u0.w), x0, acc.w);
      s += x0;
    }
    __syncthreads();
  }
  accl[w][lane] = acc;
  sl[w][lane] = s;
  __syncthreads();
  if (tid < 64){
    float4 a0 = accl[0][tid], a1 = accl[1][tid], a2 = accl[2][tid], a3 = accl[3][tid];
    float st = sl[0][tid] + sl[1][tid] + sl[2][tid] + sl[3][tid];
    float inv = 1.0f / (st + EPSV);
    float4 bb = ((const float4*)b1)[tid];
    float4 r;
    r.x = fmaf(a0.x + a1.x + a2.x + a3.x, inv, bb.x);
    r.y = fmaf(a0.y + a1.y + a2.y + a3.y, inv, bb.y);
    r.z = fmaf(a0.z + a1.z + a2.z + a3.z, inv, bb.z);
    r.w = fmaf(a0.w + a1.w + a2.w + a3.w, inv, bb.w);
    r.x = fmaxf(r.x, 0.f); r.y = fmaxf(r.y, 0.f);
    r.z = fmaxf(r.z, 0.f); r.w = fmaxf(r.w, 0.f);
    ((float4*)z1)[(size_t)node*64 + tid] = r;
  }
}

// ---------------- fused softmax + aggregation, layer 2 ----------------
__global__ __launch_bounds__(256) void k_agg2(const int* __restrict__ rs, const int* __restrict__ csr_s,
                                              const float* __restrict__ als, const float* __restrict__ ald,
                                              const float* __restrict__ h2, const float* __restrict__ b2,
                                              int N, float* __restrict__ z2){
  int tid = threadIdx.x;
  int node = blockIdx.x*4 + (tid >> 6);
  if (node >= N) return;
  int lane = tid & 63;
  int slot = lane >> 3;      // 0..7
  int q    = lane & 7;       // channels q*4..q*4+3
  int head = q >> 2;
  float aldn = ald[node*2 + head];
  int beg = rs[node], end = rs[node+1];
  float4 acc = make_float4(0.f,0.f,0.f,0.f);
  float s = 0.f;
  for (int i = beg + slot; i < end; i += 8){
    int s0 = csr_s[i];
    float x0 = __expf(lrelu(als[s0*2+head] + aldn));
    float4 v0 = ((const float4*)h2)[(size_t)s0*8 + q];
    acc.x = fmaf(v0.x, x0, acc.x); acc.y = fmaf(v0.y, x0, acc.y);
    acc.z = fmaf(v0.z, x0, acc.z); acc.w = fmaf(v0.w, x0, acc.w);
    s += x0;
  }
  #pragma unroll
  for (int o = 8; o < 64; o <<= 1){
    acc.x += __shfl_xor(acc.x, o, 64); acc.y += __shfl_xor(acc.y, o, 64);
    acc.z += __shfl_xor(acc.z, o, 64); acc.w += __shfl_xor(acc.w, o, 64);
    s += __shfl_xor(s, o, 64);
  }
  if (slot == 0){
    float inv = 1.0f / (s + EPSV);
    float4 bb = ((const float4*)b2)[q];
    float4 r;
    r.x = fmaf(acc.x, inv, bb.x); r.y = fmaf(acc.y, inv, bb.y);
    r.z = fmaf(acc.z, inv, bb.z); r.w = fmaf(acc.w, inv, bb.w);
    ((float4*)z2)[(size_t)node*8 + q] = r;
  }
}

// ---------------- decode: 8 lanes per query, float4 ----------------
__global__ void k_decode(const int* __restrict__ eli, int NQ,
                         const float* __restrict__ z2, float* __restrict__ out){
  int t = blockIdx.x*blockDim.x + threadIdx.x;
  if (t >= NQ*8) return;
  int qq = t >> 3, q = t & 7;
  int a = eli[qq], b = eli[NQ + qq];
  float4 va = ((const float4*)z2)[(size_t)a*8 + q];
  float4 vb = ((const float4*)z2)[(size_t)b*8 + q];
  float p = va.x*vb.x + va.y*vb.y + va.z*vb.z + va.w*vb.w;
  p += __shfl_xor(p, 1, 64); p += __shfl_xor(p, 2, 64); p += __shfl_xor(p, 4, 64);
  if (q == 0) out[qq] = p;
}

extern "C" void kernel_launch(void* const* d_in, const int* in_sizes, int n_in,
                              void* d_out, int out_size, void* d_ws, size_t ws_size,
                              hipStream_t stream) {
  const float* x   = (const float*)d_in[0];
  const int*   ei  = (const int*)d_in[1];
  const int*   eli = (const int*)d_in[2];
  const float* W1  = (const float*)d_in[3];
  const float* a1s = (const float*)d_in[4];
  const float* a1d = (const float*)d_in[5];
  const float* b1  = (const float*)d_in[6];
  const float* W2  = (const float*)d_in[7];
  const float* a2s = (const float*)d_in[8];
  const float* a2d = (const float*)d_in[9];
  const float* b2  = (const float*)d_in[10];
  float* out = (float*)d_out;

  int N  = in_sizes[0] / 128;
  int E  = in_sizes[1] / 2;
  int NQ = in_sizes[2] / 2;
  int ET = E + N;

  char* base = (char*)d_ws;
  size_t off = 0;
  auto alloc = [&](size_t elems)->char*{ char* r = base + off; off += elems*4; return r; };
  int*   deg   = (int*)  alloc(N);
  int*   cnt   = (int*)  alloc(N);
  int*   bsum  = (int*)  alloc(1024);
  int*   rs    = (int*)  alloc(N+1);
  int*   csr_s = (int*)  alloc(ET);
  float* al1s  = (float*)alloc((size_t)N*4);
  float* al1d  = (float*)alloc((size_t)N*4);
  float* al2s  = (float*)alloc((size_t)N*2);
  float* al2d  = (float*)alloc((size_t)N*2);
  unsigned short* h1b = (unsigned short*)alloc((size_t)N*128);  // N*256 bf16
  float* z1    = (float*)alloc((size_t)N*256);
  float* h2    = (float*)alloc((size_t)N*32);
  float* z2    = (float*)alloc((size_t)N*32);
  (void)ws_size; (void)n_in; (void)out_size;

  {
    void* args[] = {(void*)&ei, (void*)&E, (void*)&N, (void*)&deg, (void*)&cnt,
                    (void*)&rs, (void*)&csr_s, (void*)&bsum};
    hipLaunchCooperativeKernel((void*)k_csr, dim3(1024), dim3(256), args, 0, stream);
  }

  k_gemm1<<<(N+7)/8, 256, 0, stream>>>(x, W1, a1s, a1d, N, h1b, al1s, al1d);
  k_agg1<<<N, 256, 0, stream>>>(rs, csr_s, al1s, al1d, h1b, b1, N, z1);

  k_gemm2<<<(N+7)/8, 256, 0, stream>>>(z1, W2, a2s, a2d, N, h2, al2s, al2d);
  k_agg2<<<(N+3)/4, 256, 0, stream>>>(rs, csr_s, al2s, al2d, h2, b2, N, z2);

  k_decode<<<((long long)NQ*8+255)/256, 256, 0, stream>>>(eli, NQ, z2, out);
}

// Round 13
// 489.051 us; speedup vs baseline: 1.8675x; 1.8675x over previous
//
#include <hip/hip_runtime.h>

#define NEG_SLOPE 0.2f
#define EPSV 1e-16f

__device__ __forceinline__ float lrelu(float e){ return (e > 0.f) ? e : NEG_SLOPE*e; }
__device__ __forceinline__ float bf2f(unsigned short u){ return __uint_as_float((unsigned)u << 16); }
__device__ __forceinline__ unsigned short f2bf(float f){
  unsigned u = __float_as_uint(f);
  u += 0x7FFFu + ((u >> 16) & 1u);        // RTNE
  return (unsigned short)(u >> 16);
}

// ---------------- CSR build (by dst): 3 small kernels + memset ----------------
__global__ void k_deg(const int* __restrict__ ei, int E, int N, int* __restrict__ deg){
  int t = blockIdx.x*blockDim.x + threadIdx.x;
  int ET = E + N;
  if (t >= ET) return;
  int dst = (t < E) ? ei[E + t] : (t - E);
  atomicAdd(&deg[dst], 1);
}

__global__ void k_scan(const int* __restrict__ deg, int N, int* __restrict__ rs){
  __shared__ int sums[1024];
  int tid = threadIdx.x;
  int chunk = (N + 1023) >> 10;
  int s = tid*chunk, e = min(s+chunk, N);
  int sum = 0;
  for (int i = s; i < e; ++i) sum += deg[i];
  sums[tid] = sum;
  __syncthreads();
  for (int off = 1; off < 1024; off <<= 1){
    int v = (tid >= off) ? sums[tid-off] : 0;
    __syncthreads();
    sums[tid] += v;
    __syncthreads();
  }
  int run = (tid == 0) ? 0 : sums[tid-1];
  for (int i = s; i < e; ++i){ rs[i] = run; run += deg[i]; }
  if (tid == 1023) rs[N] = run;
}

__global__ void k_fill(const int* __restrict__ ei, int E, int N,
                       const int* __restrict__ rs, int* __restrict__ cnt,
                       int* __restrict__ csr_s){
  int t = blockIdx.x*blockDim.x + threadIdx.x;
  int ET = E + N;
  if (t >= ET) return;
  int src, dst;
  if (t < E){ src = ei[t]; dst = ei[E + t]; } else { src = dst = t - E; }
  int pos = atomicAdd(&cnt[dst], 1);
  csr_s[rs[dst] + pos] = src;
}

// ---------------- layer 1 GEMM: h1 (bf16) = x @ W1, plus per-node attention terms ----------------
__global__ __launch_bounds__(256) void k_gemm1(const float* __restrict__ x, const float* __restrict__ W1,
                                               const float* __restrict__ a1s, const float* __restrict__ a1d,
                                               int N, unsigned short* __restrict__ h1b,
                                               float* __restrict__ als, float* __restrict__ ald){
  __shared__ float xs[8][128];
  int bn = blockIdx.x * 8;
  int tid = threadIdx.x;
  {
    int m = tid >> 5, k4 = tid & 31;       // one float4 per thread
    int node = bn + m;
    float4 v = (node < N) ? ((const float4*)x)[(size_t)node*32 + k4]
                          : make_float4(0.f,0.f,0.f,0.f);
    ((float4*)xs[m])[k4] = v;
  }
  __syncthreads();
  float acc[8];
  #pragma unroll
  for (int m = 0; m < 8; ++m) acc[m] = 0.f;
  int j = tid;
  for (int k = 0; k < 128; ++k){
    float w = W1[k*256 + j];
    #pragma unroll
    for (int m = 0; m < 8; ++m) acc[m] = fmaf(xs[m][k], w, acc[m]);
  }
  int head = j >> 6;
  int lane = j & 63;
  float cas = a1s[head*64 + lane];
  float cad = a1d[head*64 + lane];
  #pragma unroll
  for (int m = 0; m < 8; ++m){
    int node = bn + m;
    if (node < N) h1b[(size_t)node*256 + j] = f2bf(acc[m]);
    float vs = acc[m]*cas, vd = acc[m]*cad;
    #pragma unroll
    for (int o = 32; o; o >>= 1){ vs += __shfl_xor(vs, o, 64); vd += __shfl_xor(vd, o, 64); }
    if (lane == 0 && node < N){ als[node*4+head] = vs; ald[node*4+head] = vd; }
  }
}

// ---------------- layer 2 GEMM ----------------
__global__ __launch_bounds__(256) void k_gemm2(const float* __restrict__ z1, const float* __restrict__ W2,
                                               const float* __restrict__ a2s, const float* __restrict__ a2d,
                                               int N, float* __restrict__ h2,
                                               float* __restrict__ als, float* __restrict__ ald){
  __shared__ float zs[8][256];
  int bn = blockIdx.x * 8;
  int tid = threadIdx.x;
  {
    int m = tid >> 6, k4 = tid & 63;       // two float4 per thread
    int node = bn + m;
    const float4 zero = make_float4(0.f,0.f,0.f,0.f);
    ((float4*)zs[m])[k4]      = (node < N)   ? ((const float4*)z1)[(size_t)node*64 + k4] : zero;
    int m2 = m + 4, node2 = bn + m2;
    ((float4*)zs[m2])[k4]     = (node2 < N)  ? ((const float4*)z1)[(size_t)node2*64 + k4] : zero;
  }
  __syncthreads();
  int j = tid & 31;   // out channel
  int m = tid >> 5;   // node in block
  float acc = 0.f;
  for (int k = 0; k < 256; ++k) acc = fmaf(zs[m][k], W2[k*32 + j], acc);
  int node = bn + m;
  int head = j >> 4, lane = j & 15;
  if (node < N) h2[(size_t)node*32 + j] = acc;
  float vs = acc * a2s[head*16 + lane];
  float vd = acc * a2d[head*16 + lane];
  #pragma unroll
  for (int o = 8; o; o >>= 1){ vs += __shfl_xor(vs, o, 64); vd += __shfl_xor(vd, o, 64); }
  if (lane == 0 && node < N){ als[node*2+head] = vs; ald[node*2+head] = vd; }
}

// ---------------- fused softmax + aggregation, layer 1 (bf16 h1 gather) ----------------
__global__ __launch_bounds__(256) void k_agg1(const int* __restrict__ rs, const int* __restrict__ csr_s,
                                              const float* __restrict__ als, const float* __restrict__ ald,
                                              const unsigned short* __restrict__ h1b, const float* __restrict__ b1,
                                              int N, float* __restrict__ z1){
  __shared__ int    sidx[256];
  __shared__ float  sexp[256*4];
  __shared__ float4 accl[4][64];
  __shared__ float  sl[4][64];
  int node = blockIdx.x;
  int tid = threadIdx.x;
  int w = tid >> 6, lane = tid & 63;
  int head = lane >> 4;
  int beg = rs[node], end = rs[node+1];
  const ushort4* h1v = (const ushort4*)h1b;      // 4 bf16 (8B) per lane; row = 64 ushort4
  float4 acc = make_float4(0.f,0.f,0.f,0.f);
  float s = 0.f;
  for (int base = beg; base < end; base += 256){
    int cnt = min(256, end - base);
    if (tid < cnt) sidx[tid] = csr_s[base + tid];
    __syncthreads();
    for (int t = tid; t < cnt*4; t += 256){
      int e = t >> 2, h = t & 3;
      int sv = sidx[e];
      sexp[t] = __expf(lrelu(als[sv*4 + h] + ald[node*4 + h]));
    }
    __syncthreads();
    int e = w;
    for (; e + 12 < cnt; e += 16){
      int s0 = sidx[e], s1 = sidx[e+4], s2 = sidx[e+8], s3 = sidx[e+12];
      float x0 = sexp[e*4+head], x1 = sexp[(e+4)*4+head];
      float x2 = sexp[(e+8)*4+head], x3 = sexp[(e+12)*4+head];
      ushort4 u0 = h1v[(size_t)s0*64 + lane];
      ushort4 u1 = h1v[(size_t)s1*64 + lane];
      ushort4 u2 = h1v[(size_t)s2*64 + lane];
      ushort4 u3 = h1v[(size_t)s3*64 + lane];
      acc.x = fmaf(bf2f(u0.x), x0, acc.x); acc.y = fmaf(bf2f(u0.y), x0, acc.y);
      acc.z = fmaf(bf2f(u0.z), x0, acc.z); acc.w = fmaf(bf2f(u0.w), x0, acc.w);
      acc.x = fmaf(bf2f(u1.x), x1, acc.x); acc.y = fmaf(bf2f(u1.y), x1, acc.y);
      acc.z = fmaf(bf2f(u1.z), x1, acc.z); acc.w = fmaf(bf2f(u1.w), x1, acc.w);
      acc.x = fmaf(bf2f(u2.x), x2, acc.x); acc.y = fmaf(bf2f(u2.y), x2, acc.y);
      acc.z = fmaf(bf2f(u2.z), x2, acc.z); acc.w = fmaf(bf2f(u2.w), x2, acc.w);
      acc.x = fmaf(bf2f(u3.x), x3, acc.x); acc.y = fmaf(bf2f(u3.y), x3, acc.y);
      acc.z = fmaf(bf2f(u3.z), x3, acc.z); acc.w = fmaf(bf2f(u3.w), x3, acc.w);
      s += (x0 + x1) + (x2 + x3);
    }
    for (; e < cnt; e += 4){
      int s0 = sidx[e];
      float x0 = sexp[e*4+head];
      ushort4 u0 = h1v[(size_t)s0*64 + lane];
      acc.x = fmaf(bf2f(u0.x), x0, acc.x); acc.y = fmaf(bf2f(u0.y), x0, acc.y);
      acc.z = fmaf(bf2f(u0.z), x0, acc.z); acc.w = fmaf(bf2f(u0.w), x0, acc.w);
      s += x0;
    }
    __syncthreads();
  }
  accl[w][lane] = acc;
  sl[w][lane] = s;
  __syncthreads();
  if (tid < 64){
    float4 a0 = accl[0][tid], a1 = accl[1][tid], a2 = accl[2][tid], a3 = accl[3][tid];
    float st = sl[0][tid] + sl[1][tid] + sl[2][tid] + sl[3][tid];
    float inv = 1.0f / (st + EPSV);
    float4 bb = ((const float4*)b1)[tid];
    float4 r;
    r.x = fmaf(a0.x + a1.x + a2.x + a3.x, inv, bb.x);
    r.y = fmaf(a0.y + a1.y + a2.y + a3.y, inv, bb.y);
    r.z = fmaf(a0.z + a1.z + a2.z + a3.z, inv, bb.z);
    r.w = fmaf(a0.w + a1.w + a2.w + a3.w, inv, bb.w);
    r.x = fmaxf(r.x, 0.f); r.y = fmaxf(r.y, 0.f);
    r.z = fmaxf(r.z, 0.f); r.w = fmaxf(r.w, 0.f);
    ((float4*)z1)[(size_t)node*64 + tid] = r;
  }
}

// ---------------- fused softmax + aggregation, layer 2 ----------------
__global__ __launch_bounds__(256) void k_agg2(const int* __restrict__ rs, const int* __restrict__ csr_s,
                                              const float* __restrict__ als, const float* __restrict__ ald,
                                              const float* __restrict__ h2, const float* __restrict__ b2,
                                              int N, float* __restrict__ z2){
  int tid = threadIdx.x;
  int node = blockIdx.x*4 + (tid >> 6);
  if (node >= N) return;
  int lane = tid & 63;
  int slot = lane >> 3;      // 0..7
  int q    = lane & 7;       // channels q*4..q*4+3
  int head = q >> 2;
  float aldn = ald[node*2 + head];
  int beg = rs[node], end = rs[node+1];
  float4 acc = make_float4(0.f,0.f,0.f,0.f);
  float s = 0.f;
  for (int i = beg + slot; i < end; i += 8){
    int s0 = csr_s[i];
    float x0 = __expf(lrelu(als[s0*2+head] + aldn));
    float4 v0 = ((const float4*)h2)[(size_t)s0*8 + q];
    acc.x = fmaf(v0.x, x0, acc.x); acc.y = fmaf(v0.y, x0, acc.y);
    acc.z = fmaf(v0.z, x0, acc.z); acc.w = fmaf(v0.w, x0, acc.w);
    s += x0;
  }
  #pragma unroll
  for (int o = 8; o < 64; o <<= 1){
    acc.x += __shfl_xor(acc.x, o, 64); acc.y += __shfl_xor(acc.y, o, 64);
    acc.z += __shfl_xor(acc.z, o, 64); acc.w += __shfl_xor(acc.w, o, 64);
    s += __shfl_xor(s, o, 64);
  }
  if (slot == 0){
    float inv = 1.0f / (s + EPSV);
    float4 bb = ((const float4*)b2)[q];
    float4 r;
    r.x = fmaf(acc.x, inv, bb.x); r.y = fmaf(acc.y, inv, bb.y);
    r.z = fmaf(acc.z, inv, bb.z); r.w = fmaf(acc.w, inv, bb.w);
    ((float4*)z2)[(size_t)node*8 + q] = r;
  }
}

// ---------------- decode: 8 lanes per query, float4 ----------------
__global__ void k_decode(const int* __restrict__ eli, int NQ,
                         const float* __restrict__ z2, float* __restrict__ out){
  int t = blockIdx.x*blockDim.x + threadIdx.x;
  if (t >= NQ*8) return;
  int qq = t >> 3, q = t & 7;
  int a = eli[qq], b = eli[NQ + qq];
  float4 va = ((const float4*)z2)[(size_t)a*8 + q];
  float4 vb = ((const float4*)z2)[(size_t)b*8 + q];
  float p = va.x*vb.x + va.y*vb.y + va.z*vb.z + va.w*vb.w;
  p += __shfl_xor(p, 1, 64); p += __shfl_xor(p, 2, 64); p += __shfl_xor(p, 4, 64);
  if (q == 0) out[qq] = p;
}

extern "C" void kernel_launch(void* const* d_in, const int* in_sizes, int n_in,
                              void* d_out, int out_size, void* d_ws, size_t ws_size,
                              hipStream_t stream) {
  const float* x   = (const float*)d_in[0];
  const int*   ei  = (const int*)d_in[1];
  const int*   eli = (const int*)d_in[2];
  const float* W1  = (const float*)d_in[3];
  const float* a1s = (const float*)d_in[4];
  const float* a1d = (const float*)d_in[5];
  const float* b1  = (const float*)d_in[6];
  const float* W2  = (const float*)d_in[7];
  const float* a2s = (const float*)d_in[8];
  const float* a2d = (const float*)d_in[9];
  const float* b2  = (const float*)d_in[10];
  float* out = (float*)d_out;

  int N  = in_sizes[0] / 128;
  int E  = in_sizes[1] / 2;
  int NQ = in_sizes[2] / 2;
  int ET = E + N;

  char* base = (char*)d_ws;
  size_t off = 0;
  auto alloc = [&](size_t elems)->char*{ char* r = base + off; off += elems*4; return r; };
  int*   deg   = (int*)  alloc(N);
  int*   cnt   = (int*)  alloc(N);
  size_t zbytes = off;                 // only deg+cnt must start zeroed
  int*   rs    = (int*)  alloc(N+1);
  int*   csr_s = (int*)  alloc(ET);
  float* al1s  = (float*)alloc((size_t)N*4);
  float* al1d  = (float*)alloc((size_t)N*4);
  float* al2s  = (float*)alloc((size_t)N*2);
  float* al2d  = (float*)alloc((size_t)N*2);
  unsigned short* h1b = (unsigned short*)alloc((size_t)N*128);  // N*256 bf16
  float* z1    = (float*)alloc((size_t)N*256);
  float* h2    = (float*)alloc((size_t)N*32);
  float* z2    = (float*)alloc((size_t)N*32);
  (void)ws_size; (void)n_in; (void)out_size;

  hipMemsetAsync(d_ws, 0, zbytes, stream);

  k_deg <<<(ET+255)/256, 256, 0, stream>>>(ei, E, N, deg);
  k_scan<<<1, 1024, 0, stream>>>(deg, N, rs);
  k_fill<<<(ET+255)/256, 256, 0, stream>>>(ei, E, N, rs, cnt, csr_s);

  k_gemm1<<<(N+7)/8, 256, 0, stream>>>(x, W1, a1s, a1d, N, h1b, al1s, al1d);
  k_agg1<<<N, 256, 0, stream>>>(rs, csr_s, al1s, al1d, h1b, b1, N, z1);

  k_gemm2<<<(N+7)/8, 256, 0, stream>>>(z1, W2, a2s, a2d, N, h2, al2s, al2d);
  k_agg2<<<(N+3)/4, 256, 0, stream>>>(rs, csr_s, al2s, al2d, h2, b2, N, z2);

  k_decode<<<((long long)NQ*8+255)/256, 256, 0, stream>>>(eli, NQ, z2, out);
}

// Round 16
// 465.948 us; speedup vs baseline: 1.9601x; 1.0496x over previous
//
#include <hip/hip_runtime.h>

#define NEG_SLOPE 0.2f
#define EPSV 1e-16f

typedef _Float16 half8 __attribute__((ext_vector_type(8)));
typedef float f32x4 __attribute__((ext_vector_type(4)));

__device__ __forceinline__ float lrelu(float e){ return (e > 0.f) ? e : NEG_SLOPE*e; }
__device__ __forceinline__ float bf2f(unsigned short u){ return __uint_as_float((unsigned)u << 16); }
__device__ __forceinline__ unsigned short f2bf(float f){
  unsigned u = __float_as_uint(f);
  u += 0x7FFFu + ((u >> 16) & 1u);        // RTNE
  return (unsigned short)(u >> 16);
}

// ---------------- CSR build (by dst): 3 small kernels + memset ----------------
__global__ void k_deg(const int* __restrict__ ei, int E, int N, int* __restrict__ deg){
  int t = blockIdx.x*blockDim.x + threadIdx.x;
  int ET = E + N;
  if (t >= ET) return;
  int dst = (t < E) ? ei[E + t] : (t - E);
  atomicAdd(&deg[dst], 1);
}

__global__ void k_scan(const int* __restrict__ deg, int N, int* __restrict__ rs){
  __shared__ int sums[1024];
  int tid = threadIdx.x;
  int chunk = (N + 1023) >> 10;
  int s = tid*chunk, e = min(s+chunk, N);
  int sum = 0;
  for (int i = s; i < e; ++i) sum += deg[i];
  sums[tid] = sum;
  __syncthreads();
  for (int off = 1; off < 1024; off <<= 1){
    int v = (tid >= off) ? sums[tid-off] : 0;
    __syncthreads();
    sums[tid] += v;
    __syncthreads();
  }
  int run = (tid == 0) ? 0 : sums[tid-1];
  for (int i = s; i < e; ++i){ rs[i] = run; run += deg[i]; }
  if (tid == 1023) rs[N] = run;
}

__global__ void k_fill(const int* __restrict__ ei, int E, int N,
                       const int* __restrict__ rs, int* __restrict__ cnt,
                       int* __restrict__ csr_s){
  int t = blockIdx.x*blockDim.x + threadIdx.x;
  int ET = E + N;
  if (t >= ET) return;
  int src, dst;
  if (t < E){ src = ei[t]; dst = ei[E + t]; } else { src = dst = t - E; }
  int pos = atomicAdd(&cnt[dst], 1);
  csr_s[rs[dst] + pos] = src;
}

// ---------------- prep: x -> fp16 row-major, W1 -> fp16 transposed [256][128] ----------------
__global__ void k_prep(const float* __restrict__ x, const float* __restrict__ W1, int N,
                       _Float16* __restrict__ x16, _Float16* __restrict__ W1t){
  int gs = gridDim.x*blockDim.x;
  int t = blockIdx.x*blockDim.x + threadIdx.x;
  int totx = N*128;
  for (int i = t; i < totx; i += gs) x16[i] = (_Float16)x[i];
  for (int i = t; i < 128*256; i += gs){
    int k = i >> 8, n = i & 255;
    W1t[n*128 + k] = (_Float16)W1[i];
  }
}

// ---------------- layer 1 GEMM via MFMA fp16: h1b(bf16) = x @ W1, fused als/ald ----------------
// One wave per 16 nodes. A: row=lane&15, k=(lane>>4)*8+e. B: col=lane&15, same k.
// C: col=lane&15, row=(lane>>4)*4+r.
__global__ __launch_bounds__(256) void k_gemm1m(const _Float16* __restrict__ x16,
                                                const _Float16* __restrict__ W1t,
                                                const float* __restrict__ a1s, const float* __restrict__ a1d,
                                                int N, unsigned short* __restrict__ h1b,
                                                float* __restrict__ als, float* __restrict__ ald){
  int wid = threadIdx.x >> 6;
  int lane = threadIdx.x & 63;
  int node0 = (blockIdx.x*4 + wid) * 16;
  if (node0 >= N) return;                       // wave-uniform
  int col = lane & 15;                          // A-row / B-col / C-col
  int kb8 = (lane >> 4) * 8;
  int nodeA = node0 + col; if (nodeA > N-1) nodeA = N-1;

  half8 a[4];
  #pragma unroll
  for (int kb = 0; kb < 4; ++kb)
    a[kb] = *(const half8*)(x16 + (size_t)nodeA*128 + kb*32 + kb8);

  int rbase = (lane >> 4) * 4;                  // C row base for this lane
  #pragma unroll
  for (int hg = 0; hg < 4; ++hg){               // head group = 4 N-tiles = 64 channels
    float as_p[4] = {0.f,0.f,0.f,0.f};
    float ad_p[4] = {0.f,0.f,0.f,0.f};
    #pragma unroll
    for (int nti = 0; nti < 4; ++nti){
      int nt = hg*4 + nti;
      f32x4 acc = {0.f,0.f,0.f,0.f};
      #pragma unroll
      for (int kb = 0; kb < 4; ++kb){
        half8 b = *(const half8*)(W1t + (size_t)(nt*16 + col)*128 + kb*32 + kb8);
        acc = __builtin_amdgcn_mfma_f32_16x16x32_f16(a[kb], b, acc, 0, 0, 0);
      }
      int ch  = nt*16 + col;                    // global channel
      float cas = a1s[hg*64 + (ch & 63)];
      float cad = a1d[hg*64 + (ch & 63)];
      #pragma unroll
      for (int r = 0; r < 4; ++r){
        int nd = node0 + rbase + r;
        if (nd < N) h1b[(size_t)nd*256 + ch] = f2bf(acc[r]);
        as_p[r] = fmaf(acc[r], cas, as_p[r]);
        ad_p[r] = fmaf(acc[r], cad, ad_p[r]);
      }
    }
    #pragma unroll
    for (int r = 0; r < 4; ++r){
      float vs = as_p[r], vd = ad_p[r];
      #pragma unroll
      for (int o = 1; o < 16; o <<= 1){ vs += __shfl_xor(vs, o, 64); vd += __shfl_xor(vd, o, 64); }
      if (col == 0){
        int nd = node0 + rbase + r;
        if (nd < N){ als[nd*4 + hg] = vs; ald[nd*4 + hg] = vd; }
      }
    }
  }
}

// ---------------- layer 2 GEMM ----------------
__global__ __launch_bounds__(256) void k_gemm2(const float* __restrict__ z1, const float* __restrict__ W2,
                                               const float* __restrict__ a2s, const float* __restrict__ a2d,
                                               int N, float* __restrict__ h2,
                                               float* __restrict__ als, float* __restrict__ ald){
  __shared__ float zs[8][256];
  int bn = blockIdx.x * 8;
  int tid = threadIdx.x;
  {
    int m = tid >> 6, k4 = tid & 63;       // two float4 per thread
    int node = bn + m;
    const float4 zero = make_float4(0.f,0.f,0.f,0.f);
    ((float4*)zs[m])[k4]      = (node < N)   ? ((const float4*)z1)[(size_t)node*64 + k4] : zero;
    int m2 = m + 4, node2 = bn + m2;
    ((float4*)zs[m2])[k4]     = (node2 < N)  ? ((const float4*)z1)[(size_t)node2*64 + k4] : zero;
  }
  __syncthreads();
  int j = tid & 31;   // out channel
  int m = tid >> 5;   // node in block
  float acc = 0.f;
  for (int k = 0; k < 256; ++k) acc = fmaf(zs[m][k], W2[k*32 + j], acc);
  int node = bn + m;
  int head = j >> 4, lane = j & 15;
  if (node < N) h2[(size_t)node*32 + j] = acc;
  float vs = acc * a2s[head*16 + lane];
  float vd = acc * a2d[head*16 + lane];
  #pragma unroll
  for (int o = 8; o; o >>= 1){ vs += __shfl_xor(vs, o, 64); vd += __shfl_xor(vd, o, 64); }
  if (lane == 0 && node < N){ als[node*2+head] = vs; ald[node*2+head] = vd; }
}

// ---------------- fused softmax + aggregation, layer 1 (bf16 h1 gather) ----------------
__global__ __launch_bounds__(256) void k_agg1(const int* __restrict__ rs, const int* __restrict__ csr_s,
                                              const float* __restrict__ als, const float* __restrict__ ald,
                                              const unsigned short* __restrict__ h1b, const float* __restrict__ b1,
                                              int N, float* __restrict__ z1){
  __shared__ int    sidx[256];
  __shared__ float  sexp[256*4];
  __shared__ float4 accl[4][64];
  __shared__ float  sl[4][64];
  int node = blockIdx.x;
  int tid = threadIdx.x;
  int w = tid >> 6, lane = tid & 63;
  int head = lane >> 4;
  int beg = rs[node], end = rs[node+1];
  const ushort4* h1v = (const ushort4*)h1b;      // 4 bf16 (8B) per lane; row = 64 ushort4
  float4 acc = make_float4(0.f,0.f,0.f,0.f);
  float s = 0.f;
  for (int base = beg; base < end; base += 256){
    int cnt = min(256, end - base);
    if (tid < cnt) sidx[tid] = csr_s[base + tid];
    __syncthreads();
    for (int t = tid; t < cnt*4; t += 256){
      int e = t >> 2, h = t & 3;
      int sv = sidx[e];
      sexp[t] = __expf(lrelu(als[sv*4 + h] + ald[node*4 + h]));
    }
    __syncthreads();
    int e = w;
    for (; e + 12 < cnt; e += 16){
      int s0 = sidx[e], s1 = sidx[e+4], s2 = sidx[e+8], s3 = sidx[e+12];
      float x0 = sexp[e*4+head], x1 = sexp[(e+4)*4+head];
      float x2 = sexp[(e+8)*4+head], x3 = sexp[(e+12)*4+head];
      ushort4 u0 = h1v[(size_t)s0*64 + lane];
      ushort4 u1 = h1v[(size_t)s1*64 + lane];
      ushort4 u2 = h1v[(size_t)s2*64 + lane];
      ushort4 u3 = h1v[(size_t)s3*64 + lane];
      acc.x = fmaf(bf2f(u0.x), x0, acc.x); acc.y = fmaf(bf2f(u0.y), x0, acc.y);
      acc.z = fmaf(bf2f(u0.z), x0, acc.z); acc.w = fmaf(bf2f(u0.w), x0, acc.w);
      acc.x = fmaf(bf2f(u1.x), x1, acc.x); acc.y = fmaf(bf2f(u1.y), x1, acc.y);
      acc.z = fmaf(bf2f(u1.z), x1, acc.z); acc.w = fmaf(bf2f(u1.w), x1, acc.w);
      acc.x = fmaf(bf2f(u2.x), x2, acc.x); acc.y = fmaf(bf2f(u2.y), x2, acc.y);
      acc.z = fmaf(bf2f(u2.z), x2, acc.z); acc.w = fmaf(bf2f(u2.w), x2, acc.w);
      acc.x = fmaf(bf2f(u3.x), x3, acc.x); acc.y = fmaf(bf2f(u3.y), x3, acc.y);
      acc.z = fmaf(bf2f(u3.z), x3, acc.z); acc.w = fmaf(bf2f(u3.w), x3, acc.w);
      s += (x0 + x1) + (x2 + x3);
    }
    for (; e < cnt; e += 4){
      int s0 = sidx[e];
      float x0 = sexp[e*4+head];
      ushort4 u0 = h1v[(size_t)s0*64 + lane];
      acc.x = fmaf(bf2f(u0.x), x0, acc.x); acc.y = fmaf(bf2f(u0.y), x0, acc.y);
      acc.z = fmaf(bf2f(u0.z), x0, acc.z); acc.w = fmaf(bf2f(u0.w), x0, acc.w);
      s += x0;
    }
    __syncthreads();
  }
  accl[w][lane] = acc;
  sl[w][lane] = s;
  __syncthreads();
  if (tid < 64){
    float4 a0 = accl[0][tid], a1 = accl[1][tid], a2 = accl[2][tid], a3 = accl[3][tid];
    float st = sl[0][tid] + sl[1][tid] + sl[2][tid] + sl[3][tid];
    float inv = 1.0f / (st + EPSV);
    float4 bb = ((const float4*)b1)[tid];
    float4 r;
    r.x = fmaf(a0.x + a1.x + a2.x + a3.x, inv, bb.x);
    r.y = fmaf(a0.y + a1.y + a2.y + a3.y, inv, bb.y);
    r.z = fmaf(a0.z + a1.z + a2.z + a3.z, inv, bb.z);
    r.w = fmaf(a0.w + a1.w + a2.w + a3.w, inv, bb.w);
    r.x = fmaxf(r.x, 0.f); r.y = fmaxf(r.y, 0.f);
    r.z = fmaxf(r.z, 0.f); r.w = fmaxf(r.w, 0.f);
    ((float4*)z1)[(size_t)node*64 + tid] = r;
  }
}

// ---------------- fused softmax + aggregation, layer 2 ----------------
__global__ __launch_bounds__(256) void k_agg2(const int* __restrict__ rs, const int* __restrict__ csr_s,
                                              const float* __restrict__ als, const float* __restrict__ ald,
                                              const float* __restrict__ h2, const float* __restrict__ b2,
                                              int N, float* __restrict__ z2){
  int tid = threadIdx.x;
  int node = blockIdx.x*4 + (tid >> 6);
  if (node >= N) return;
  int lane = tid & 63;
  int slot = lane >> 3;      // 0..7
  int q    = lane & 7;       // channels q*4..q*4+3
  int head = q >> 2;
  float aldn = ald[node*2 + head];
  int beg = rs[node], end = rs[node+1];
  float4 acc = make_float4(0.f,0.f,0.f,0.f);
  float s = 0.f;
  for (int i = beg + slot; i < end; i += 8){
    int s0 = csr_s[i];
    float x0 = __expf(lrelu(als[s0*2+head] + aldn));
    float4 v0 = ((const float4*)h2)[(size_t)s0*8 + q];
    acc.x = fmaf(v0.x, x0, acc.x); acc.y = fmaf(v0.y, x0, acc.y);
    acc.z = fmaf(v0.z, x0, acc.z); acc.w = fmaf(v0.w, x0, acc.w);
    s += x0;
  }
  #pragma unroll
  for (int o = 8; o < 64; o <<= 1){
    acc.x += __shfl_xor(acc.x, o, 64); acc.y += __shfl_xor(acc.y, o, 64);
    acc.z += __shfl_xor(acc.z, o, 64); acc.w += __shfl_xor(acc.w, o, 64);
    s += __shfl_xor(s, o, 64);
  }
  if (slot == 0){
    float inv = 1.0f / (s + EPSV);
    float4 bb = ((const float4*)b2)[q];
    float4 r;
    r.x = fmaf(acc.x, inv, bb.x); r.y = fmaf(acc.y, inv, bb.y);
    r.z = fmaf(acc.z, inv, bb.z); r.w = fmaf(acc.w, inv, bb.w);
    ((float4*)z2)[(size_t)node*8 + q] = r;
  }
}

// ---------------- decode: 8 lanes per query, float4 ----------------
__global__ void k_decode(const int* __restrict__ eli, int NQ,
                         const float* __restrict__ z2, float* __restrict__ out){
  int t = blockIdx.x*blockDim.x + threadIdx.x;
  if (t >= NQ*8) return;
  int qq = t >> 3, q = t & 7;
  int a = eli[qq], b = eli[NQ + qq];
  float4 va = ((const float4*)z2)[(size_t)a*8 + q];
  float4 vb = ((const float4*)z2)[(size_t)b*8 + q];
  float p = va.x*vb.x + va.y*vb.y + va.z*vb.z + va.w*vb.w;
  p += __shfl_xor(p, 1, 64); p += __shfl_xor(p, 2, 64); p += __shfl_xor(p, 4, 64);
  if (q == 0) out[qq] = p;
}

extern "C" void kernel_launch(void* const* d_in, const int* in_sizes, int n_in,
                              void* d_out, int out_size, void* d_ws, size_t ws_size,
                              hipStream_t stream) {
  const float* x   = (const float*)d_in[0];
  const int*   ei  = (const int*)d_in[1];
  const int*   eli = (const int*)d_in[2];
  const float* W1  = (const float*)d_in[3];
  const float* a1s = (const float*)d_in[4];
  const float* a1d = (const float*)d_in[5];
  const float* b1  = (const float*)d_in[6];
  const float* W2  = (const float*)d_in[7];
  const float* a2s = (const float*)d_in[8];
  const float* a2d = (const float*)d_in[9];
  const float* b2  = (const float*)d_in[10];
  float* out = (float*)d_out;

  int N  = in_sizes[0] / 128;
  int E  = in_sizes[1] / 2;
  int NQ = in_sizes[2] / 2;
  int ET = E + N;

  char* base = (char*)d_ws;
  size_t off = 0;
  auto alloc = [&](size_t elems)->char*{ char* r = base + off; off += elems*4; return r; };
  int*   deg   = (int*)  alloc(N);
  int*   cnt   = (int*)  alloc(N);
  size_t zbytes = off;                 // only deg+cnt must start zeroed
  int*   rs    = (int*)  alloc(N+1);
  int*   csr_s = (int*)  alloc(ET);
  float* al1s  = (float*)alloc((size_t)N*4);
  float* al1d  = (float*)alloc((size_t)N*4);
  float* al2s  = (float*)alloc((size_t)N*2);
  float* al2d  = (float*)alloc((size_t)N*2);
  unsigned short* h1b = (unsigned short*)alloc((size_t)N*128);  // N*256 bf16
  _Float16* x16 = (_Float16*)alloc((size_t)N*64);               // N*128 fp16
  _Float16* W1t = (_Float16*)alloc(16384);                      // 256*128 fp16
  float* z1    = (float*)alloc((size_t)N*256);
  float* h2    = (float*)alloc((size_t)N*32);
  float* z2    = (float*)alloc((size_t)N*32);
  (void)ws_size; (void)n_in; (void)out_size;

  hipMemsetAsync(d_ws, 0, zbytes, stream);

  k_deg <<<(ET+255)/256, 256, 0, stream>>>(ei, E, N, deg);
  k_scan<<<1, 1024, 0, stream>>>(deg, N, rs);
  k_fill<<<(ET+255)/256, 256, 0, stream>>>(ei, E, N, rs, cnt, csr_s);

  k_prep<<<1024, 256, 0, stream>>>(x, W1, N, x16, W1t);
  k_gemm1m<<<(N + 63)/64, 256, 0, stream>>>(x16, W1t, a1s, a1d, N, h1b, al1s, al1d);
  k_agg1<<<N, 256, 0, stream>>>(rs, csr_s, al1s, al1d, h1b, b1, N, z1);

  k_gemm2<<<(N+7)/8, 256, 0, stream>>>(z1, W2, a2s, a2d, N, h2, al2s, al2d);
  k_agg2<<<(N+3)/4, 256, 0, stream>>>(rs, csr_s, al2s, al2d, h2, b2, N, z2);

  k_decode<<<((long long)NQ*8+255)/256, 256, 0, stream>>>(eli, NQ, z2, out);
}